// Round 3
// baseline (85.048 us; speedup 1.0000x reference)
//
#include <hip/hip_runtime.h>

#define CBLK 256
#define PBLK 256
#define GRID 1024          // pair-kernel blocks
#define RTILE 16           // pos values per thread in registers (covers 4096/chunk)

#define LOG2E 1.4426950408889634f
#define LN2   0.6931471805599453

__device__ __forceinline__ float fast_exp2(float x) {
#if __has_builtin(__builtin_amdgcn_exp2f)
    return __builtin_amdgcn_exp2f(x);      // v_exp_f32
#else
    return exp2f(x);
#endif
}
__device__ __forceinline__ float fast_log2(float x) {
#if __has_builtin(__builtin_amdgcn_logf)
    return __builtin_amdgcn_logf(x);       // v_log_f32
#else
    return log2f(x);
#endif
}

// ---------------------------------------------------------------------------
// Pass 1: compact pred*log2(e) into dense vpos[] (ty==1) / vneg[] (ty==0).
// Ballot-based wave compaction, one atomic per wave per list.
// cnt[0]=|pos|, cnt[1]=|neg| (zeroed by the memset node).
// ---------------------------------------------------------------------------
__global__ void compact_kernel(const float* __restrict__ v,
                               const int* __restrict__ ty,
                               int* __restrict__ cnt,
                               float* __restrict__ vpos,
                               float* __restrict__ vneg,
                               int N) {
    const int i    = blockIdx.x * blockDim.x + threadIdx.x;
    const int lane = threadIdx.x & 63;

    const bool valid = (i < N);
    float val = 0.0f;
    int   t   = -1;
    if (valid) { val = v[i] * LOG2E; t = ty[i]; }

    const bool isP = valid && (t == 1);
    const bool isN = valid && (t == 0);

    const unsigned long long mp = __ballot(isP);
    const unsigned long long mn = __ballot(isN);
    const unsigned long long lt = (lane == 0) ? 0ull : (~0ull >> (64 - lane));

    int basep = 0, basen = 0;
    if (lane == 0) {
        basep = atomicAdd(&cnt[0], __popcll(mp));
        basen = atomicAdd(&cnt[1], __popcll(mn));
    }
    basep = __shfl(basep, 0, 64);
    basen = __shfl(basen, 0, 64);

    if (isP) vpos[basep + __popcll(mp & lt)] = val;
    if (isN) vneg[basen + __popcll(mn & lt)] = val;
}

// ---------------------------------------------------------------------------
// Pass 2 (+fused finalize): sum softplus over the dense P x Q pair space.
// Thread holds RTILE pos values in registers (weight 0/1 for the tail);
// block bid iterates negs b = bid, bid+GRID, ... (wave-uniform -> s_load).
// Log2-domain: x2 = (vn-vp)*log2e already; term = max(x2,0)+log2(1+2^-|x2|);
// final result scaled by ln2. Per pair: v_sub, v_exp, v_add, v_log, v_max,
// v_add, v_fmac = 5 VALU + 2 trans.
// Last block to finish (ticket atomic + threadfence) reduces partials and
// writes out = ln2 * total / (P*Q).
// ---------------------------------------------------------------------------
__global__ __launch_bounds__(PBLK) void pair_kernel(
        const int* __restrict__ cnt,
        const float* __restrict__ vpos,
        const float* __restrict__ vneg,
        float* __restrict__ partials,
        unsigned int* __restrict__ ticket,
        float* __restrict__ out) {
    const int P   = cnt[0];
    const int Q   = cnt[1];
    const int tid = threadIdx.x;

    float acc = 0.0f;
    for (int base = 0; base < P; base += RTILE * PBLK) {
        float pv[RTILE], pw[RTILE];
        #pragma unroll
        for (int r = 0; r < RTILE; ++r) {
            const int idx = base + (r << 8) + tid;
            const bool ok = (idx < P);
            pv[r] = ok ? vpos[idx] : 0.0f;
            pw[r] = ok ? 1.0f : 0.0f;
        }
        for (int b = blockIdx.x; b < Q; b += GRID) {
            const float vn = vneg[b];          // uniform -> scalar load
            #pragma unroll
            for (int r = 0; r < RTILE; ++r) {
                const float x = vn - pv[r];
                const float e = fast_exp2(-fabsf(x));       // modifiers fold
                const float t = fmaxf(x, 0.0f) + fast_log2(1.0f + e);
                acc = fmaf(pw[r], t, acc);
            }
        }
    }

    // block reduction
    for (int off = 32; off > 0; off >>= 1)
        acc += __shfl_down(acc, off, 64);

    __shared__ float wsum[PBLK / 64];
    __shared__ int lastflag;
    const int lane = tid & 63;
    const int wid  = tid >> 6;
    if (lane == 0) wsum[wid] = acc;
    __syncthreads();
    if (tid == 0) {
        float s = 0.0f;
        #pragma unroll
        for (int w = 0; w < PBLK / 64; ++w) s += wsum[w];
        partials[blockIdx.x] = s;
        __threadfence();                               // release
        const unsigned int t = atomicAdd(ticket, 1u);  // device scope
        lastflag = (t == GRID - 1) ? 1 : 0;
    }
    __syncthreads();

    if (lastflag) {
        __threadfence();                               // acquire
        float s = 0.0f;
        for (int k = tid; k < GRID; k += PBLK) s += partials[k];
        for (int off = 32; off > 0; off >>= 1)
            s += __shfl_down(s, off, 64);
        if (lane == 0) wsum[wid] = s;
        __syncthreads();
        if (tid == 0) {
            double tot = 0.0;
            #pragma unroll
            for (int w = 0; w < PBLK / 64; ++w) tot += (double)wsum[w];
            out[0] = (float)(tot * LN2 / ((double)P * (double)Q));
        }
    }
}

extern "C" void kernel_launch(void* const* d_in, const int* in_sizes, int n_in,
                              void* d_out, int out_size, void* d_ws, size_t ws_size,
                              hipStream_t stream) {
    const float* v  = (const float*)d_in[0];   // pred_y fp32, N = n*K
    const int*   ty = (const int*)d_in[1];     // true_y int32 {0,1}
    float* out = (float*)d_out;
    const int N = in_sizes[0];

    // ws layout: [cnt0,cnt1,ticket,pad : 16B][pad to 64][vpos:N][vneg:N][partials:GRID]
    char*  ws       = (char*)d_ws;
    int*   cnt      = (int*)ws;
    unsigned int* ticket = (unsigned int*)(ws + 8);
    float* vpos     = (float*)(ws + 64);
    float* vneg     = vpos + N;
    float* partials = vneg + N;

    hipMemsetAsync(ws, 0, 16, stream);   // zero cnt + ticket (capturable node)

    const int cblocks = (N + CBLK - 1) / CBLK;
    compact_kernel<<<cblocks, CBLK, 0, stream>>>(v, ty, cnt, vpos, vneg, N);
    pair_kernel<<<GRID, PBLK, 0, stream>>>(cnt, vpos, vneg, partials, ticket, out);
}

// Round 4
// 72.629 us; speedup vs baseline: 1.1710x; 1.1710x over previous
//
#include <hip/hip_runtime.h>

#define GRID 1024          // pair-kernel blocks
#define PBLK 512           // pair-kernel threads (8 waves)
#define RT   16            // v-values per thread: PBLK*RT = 8192 = N

#define LOG2E 1.4426950408889634f
#define LN2   0.6931471805599453

__device__ __forceinline__ float fast_exp2(float x) {
#if __has_builtin(__builtin_amdgcn_exp2f)
    return __builtin_amdgcn_exp2f(x);      // v_exp_f32
#else
    return exp2f(x);
#endif
}
__device__ __forceinline__ float fast_log2(float x) {
#if __has_builtin(__builtin_amdgcn_logf)
    return __builtin_amdgcn_logf(x);       // v_log_f32
#else
    return log2f(x);
#endif
}

// ---------------------------------------------------------------------------
// One pass over the full N x N pair space, no compaction:
//   sum_{a,b} [ty[a]==1][ty[b]==0] * softplus(v[b]-v[a])
// Each thread holds RT a-values in registers (float4 loads, pre-scaled by
// log2e) plus 0/1 weights. Block bid owns b = bid + k*GRID (uniform); columns
// with ty[b]==1 are skipped by a wave-uniform branch, so real work is
// N * |neg| pairs at 5 VALU + 2 trans each (log2-domain softplus).
// Deterministic: partials[bid] written unconditionally, no atomics, no init.
// ---------------------------------------------------------------------------
__global__ __launch_bounds__(PBLK) void pair_kernel(
        const float* __restrict__ v,
        const int* __restrict__ ty,
        float* __restrict__ partials,
        int N) {
    const int tid = threadIdx.x;

    // Register-resident a-slice: elements j*(PBLK*4) + tid*4 + {0..3}
    float pa[RT], w[RT];
    const float4* v4  = (const float4*)v;
    const int4*   t4  = (const int4*)ty;
    #pragma unroll
    for (int j = 0; j < RT / 4; ++j) {
        const int q = j * PBLK + tid;      // float4 index
        const float4 vv = v4[q];
        const int4   tt = t4[q];
        pa[4*j+0] = vv.x * LOG2E;  w[4*j+0] = (tt.x == 1) ? 1.0f : 0.0f;
        pa[4*j+1] = vv.y * LOG2E;  w[4*j+1] = (tt.y == 1) ? 1.0f : 0.0f;
        pa[4*j+2] = vv.z * LOG2E;  w[4*j+2] = (tt.z == 1) ? 1.0f : 0.0f;
        pa[4*j+3] = vv.w * LOG2E;  w[4*j+3] = (tt.w == 1) ? 1.0f : 0.0f;
    }

    float acc = 0.0f;
    for (int b = blockIdx.x; b < N; b += GRID) {
        if (ty[b] != 0) continue;          // uniform -> s_cbranch skip
        const float vbl = v[b] * LOG2E;    // uniform
        #pragma unroll
        for (int r = 0; r < RT; ++r) {
            const float x = vbl - pa[r];
            const float e = fast_exp2(-fabsf(x));        // modifiers fold
            const float t = fmaxf(x, 0.0f) + fast_log2(1.0f + e);
            acc = fmaf(w[r], t, acc);
        }
    }

    // wave reduce, then cross-wave via LDS
    for (int off = 32; off > 0; off >>= 1)
        acc += __shfl_down(acc, off, 64);

    __shared__ float wsum[PBLK / 64];
    const int lane = tid & 63;
    const int wid  = tid >> 6;
    if (lane == 0) wsum[wid] = acc;
    __syncthreads();
    if (tid == 0) {
        float s = 0.0f;
        #pragma unroll
        for (int wdx = 0; wdx < PBLK / 64; ++wdx) s += wsum[wdx];
        partials[blockIdx.x] = s;          // unconditional
    }
}

// ---------------------------------------------------------------------------
// Single block: total = sum(partials); P,Q counted straight from ty;
// out = ln2 * total / (P*Q).
// ---------------------------------------------------------------------------
__global__ __launch_bounds__(PBLK) void finalize_kernel(
        const float* __restrict__ partials, int nparts,
        const int* __restrict__ ty, int N,
        float* __restrict__ out) {
    const int tid = threadIdx.x;

    double s = 0.0;
    for (int k = tid; k < nparts; k += PBLK) s += (double)partials[k];

    int cp = 0, cn = 0;
    for (int k = tid; k < N; k += PBLK) {
        const int t = ty[k];
        cp += (t == 1);
        cn += (t == 0);
    }

    __shared__ double sd[PBLK];
    __shared__ int    sp_[PBLK];
    __shared__ int    sn_[PBLK];
    sd[tid] = s; sp_[tid] = cp; sn_[tid] = cn;
    __syncthreads();
    for (int off = PBLK / 2; off > 0; off >>= 1) {
        if (tid < off) {
            sd[tid]  += sd[tid + off];
            sp_[tid] += sp_[tid + off];
            sn_[tid] += sn_[tid + off];
        }
        __syncthreads();
    }
    if (tid == 0) {
        const double denom = (double)sp_[0] * (double)sn_[0];
        out[0] = (float)(sd[0] * LN2 / denom);
    }
}

extern "C" void kernel_launch(void* const* d_in, const int* in_sizes, int n_in,
                              void* d_out, int out_size, void* d_ws, size_t ws_size,
                              hipStream_t stream) {
    const float* v  = (const float*)d_in[0];   // pred_y fp32, N = n*K = 8192
    const int*   ty = (const int*)d_in[1];     // true_y int32 {0,1}
    float* out = (float*)d_out;
    const int N = in_sizes[0];

    float* partials = (float*)d_ws;            // GRID floats, fully overwritten

    pair_kernel<<<GRID, PBLK, 0, stream>>>(v, ty, partials, N);
    finalize_kernel<<<1, PBLK, 0, stream>>>(partials, GRID, ty, N, out);
}

// Round 5
// 68.771 us; speedup vs baseline: 1.2367x; 1.0561x over previous
//
#include <hip/hip_runtime.h>

#define GRID 1024          // pair-kernel blocks
#define PBLK 512           // pair-kernel threads (8 waves)
#define RT   16            // a-values per thread: PBLK*RT = 8192 = N
#define BCH  8             // b-columns prefetched per block chunk

#define LOG2E 1.4426950408889634f
#define LN2   0.6931471805599453
#define BIGF  1.0e30f      // a-side mask bias: x = vbl - BIGF -> max=0, exp2=0

__device__ __forceinline__ float fast_exp2(float x) {
#if __has_builtin(__builtin_amdgcn_exp2f)
    return __builtin_amdgcn_exp2f(x);      // v_exp_f32
#else
    return exp2f(x);
#endif
}
__device__ __forceinline__ float fast_log2(float x) {
#if __has_builtin(__builtin_amdgcn_logf)
    return __builtin_amdgcn_logf(x);       // v_log_f32
#else
    return log2f(x);
#endif
}

// ---------------------------------------------------------------------------
//   sum_{a,b} [ty[a]==1][ty[b]==0] * softplus(v[b]-v[a])
// Log2 domain: softplus(x)/ln2 = max(x2,0) + log2(1 + 2^-|x2|), x2 = x*log2e.
// Per b-column each thread multiplies its 16 factors (1+2^-|x2|) into p
// (each factor in (1,2], so p <= 2^16: no overflow) and takes ONE log2 —
// 4 VALU + 1 trans per pair instead of 5 + 2.
// a-side mask is free: masked entries hold pa=1e30 so max(x2,0)=0 and
// exp2(-|x2|)=0 (p *= 1). b-columns with ty==1 are skipped wave-uniformly.
// Deterministic: partials[bid] written unconditionally, no atomics, no init.
// ---------------------------------------------------------------------------
__global__ __launch_bounds__(PBLK) void pair_kernel(
        const float* __restrict__ v,
        const int* __restrict__ ty,
        float* __restrict__ partials,
        int N) {
    const int tid = threadIdx.x;

    // Register-resident a-slice (float4/int4 coalesced), bias-masked.
    float pa[RT];
    const float4* v4 = (const float4*)v;
    const int4*   t4 = (const int4*)ty;
    #pragma unroll
    for (int j = 0; j < RT / 4; ++j) {
        const int q = j * PBLK + tid;      // float4 index
        const float4 vv = v4[q];
        const int4   tt = t4[q];
        pa[4*j+0] = (tt.x == 1) ? vv.x * LOG2E : BIGF;
        pa[4*j+1] = (tt.y == 1) ? vv.y * LOG2E : BIGF;
        pa[4*j+2] = (tt.z == 1) ? vv.z * LOG2E : BIGF;
        pa[4*j+3] = (tt.w == 1) ? vv.w * LOG2E : BIGF;
    }

    float accm = 0.0f;   // sum of max(x2,0) terms
    float accl = 0.0f;   // sum of log2(prod) terms

    for (int b0 = blockIdx.x; b0 < N; b0 += GRID * BCH) {
        // Prefetch this chunk's uniform b-metadata (independent s_loads).
        float vb[BCH];
        int   tb[BCH];
        #pragma unroll
        for (int k = 0; k < BCH; ++k) {
            const int b  = b0 + k * GRID;
            const bool ok = (b < N);
            vb[k] = ok ? v[b] * LOG2E : 0.0f;
            tb[k] = ok ? ty[b] : 1;          // 1 => skip
        }
        #pragma unroll
        for (int k = 0; k < BCH; ++k) {
            if (tb[k] != 0) continue;        // uniform -> scalar branch
            const float vbl = vb[k];
            float p = 1.0f;
            #pragma unroll
            for (int r = 0; r < RT; ++r) {
                const float x = vbl - pa[r];
                accm += fmaxf(x, 0.0f);
                const float e = fast_exp2(-fabsf(x));   // src mods fold
                p = fmaf(p, e, p);                      // p *= (1 + e)
            }
            accl += fast_log2(p);
        }
    }

    float acc = accm + accl;

    // wave reduce, then cross-wave via LDS
    for (int off = 32; off > 0; off >>= 1)
        acc += __shfl_down(acc, off, 64);

    __shared__ float wsum[PBLK / 64];
    const int lane = tid & 63;
    const int wid  = tid >> 6;
    if (lane == 0) wsum[wid] = acc;
    __syncthreads();
    if (tid == 0) {
        float s = 0.0f;
        #pragma unroll
        for (int wdx = 0; wdx < PBLK / 64; ++wdx) s += wsum[wdx];
        partials[blockIdx.x] = s;            // unconditional
    }
}

// ---------------------------------------------------------------------------
// Single block: total = sum(partials); P,Q counted straight from ty;
// out = ln2 * total / (P*Q).
// ---------------------------------------------------------------------------
__global__ __launch_bounds__(PBLK) void finalize_kernel(
        const float* __restrict__ partials, int nparts,
        const int* __restrict__ ty, int N,
        float* __restrict__ out) {
    const int tid = threadIdx.x;

    double s = 0.0;
    for (int k = tid; k < nparts; k += PBLK) s += (double)partials[k];

    int cp = 0, cn = 0;
    for (int k = tid; k < N; k += PBLK) {
        const int t = ty[k];
        cp += (t == 1);
        cn += (t == 0);
    }

    __shared__ double sd[PBLK];
    __shared__ int    sp_[PBLK];
    __shared__ int    sn_[PBLK];
    sd[tid] = s; sp_[tid] = cp; sn_[tid] = cn;
    __syncthreads();
    for (int off = PBLK / 2; off > 0; off >>= 1) {
        if (tid < off) {
            sd[tid]  += sd[tid + off];
            sp_[tid] += sp_[tid + off];
            sn_[tid] += sn_[tid + off];
        }
        __syncthreads();
    }
    if (tid == 0) {
        const double denom = (double)sp_[0] * (double)sn_[0];
        out[0] = (float)(sd[0] * LN2 / denom);
    }
}

extern "C" void kernel_launch(void* const* d_in, const int* in_sizes, int n_in,
                              void* d_out, int out_size, void* d_ws, size_t ws_size,
                              hipStream_t stream) {
    const float* v  = (const float*)d_in[0];   // pred_y fp32, N = n*K = 8192
    const int*   ty = (const int*)d_in[1];     // true_y int32 {0,1}
    float* out = (float*)d_out;
    const int N = in_sizes[0];

    float* partials = (float*)d_ws;            // GRID floats, fully overwritten

    pair_kernel<<<GRID, PBLK, 0, stream>>>(v, ty, partials, N);
    finalize_kernel<<<1, PBLK, 0, stream>>>(partials, GRID, ty, N, out);
}